// Round 5
// baseline (27247.278 us; speedup 1.0000x reference)
//
#include <hip/hip_runtime.h>
#include <hip/hip_fp16.h>

#define TT 1024
#define BB 64
#define HH 256
#define NQ 4          // blocks per batch group (h-slices)
#define SL 64         // HH / NQ
#define NTH 1024
#define NW 16         // waves per block

// ---- workspace byte layout ----
#define MIR_BYTES (256ull * TT * SL * 2)            // fp16 mem mirror [blk][T][64], block-private
#define STW_OFF   (MIR_BYTES)                        // st[B][H] f32, cross-block
#define EP_OFF    (STW_OFF + 1ull * BB * HH * 4)     // e-partials [B*NQ][T] f32
#define PARTS_OFF (EP_OFF + 1ull * BB * NQ * TT * 4) // uam partials [B*NQ][H] f32
#define AF_OFF    (PARTS_OFF + 1ull * BB * NQ * HH * 4)
#define BF_OFF    (AF_OFF + 1ull * BB * NQ * 32 * 4)
#define PF_OFF    (BF_OFF + 1ull * BB * NQ * 32 * 4)
#define BR_OFF    (PF_OFF + 1ull * BB * NQ * 32 * 4)
#define WS_NEED   (BR_OFF + 128)                     // ~35.0 MB

#define PM 2.88539008178f   // 2*log2(e): tanh(x) = 1 - 2/(1+2^(PM*x))

#if __has_builtin(__builtin_amdgcn_exp2f)
#define EXP2F(x) __builtin_amdgcn_exp2f(x)
#else
#define EXP2F(x) __expf(0.69314718056f * (x))
#endif

__device__ __forceinline__ float tanh_fast(float xx) {
  float e = __expf(2.0f * xx);
  return 1.0f - 2.0f * __builtin_amdgcn_rcpf(e + 1.0f);
}

#define AGT __HIP_MEMORY_SCOPE_AGENT
__device__ __forceinline__ float ld_cg(const float* p) {
  return __hip_atomic_load(p, __ATOMIC_RELAXED, AGT);
}
__device__ __forceinline__ void st_cg(float* p, float v) {
  __hip_atomic_store(p, v, __ATOMIC_RELAXED, AGT);
}

// post: drain all block stores (syncthreads => vmcnt(0)), then RELEASE RMW at
// the coherence point. The release is load-bearing: it forces prior sc1 data
// stores visible device-wide regardless of XCD placement (r3-proven; r4's
// relaxed-store variant raced when group blocks landed on different XCDs).
__device__ __forceinline__ void post1(int* slot) {
  __syncthreads();
  if (threadIdx.x == 0)
    __hip_atomic_fetch_add(slot, 1, __ATOMIC_RELEASE, AGT);
}
// wait: 4 lanes poll the group's 4 counter lines in parallel until >= val
__device__ __forceinline__ void wait4(int* base, int val, int* broken) {
  if (threadIdx.x < 4) {
    const int* f = base + threadIdx.x * 32;
    long it = 0;
    while (__hip_atomic_load(f, __ATOMIC_RELAXED, AGT) < val) {
      if (__hip_atomic_load(broken, __ATOMIC_RELAXED, AGT)) break;
      if (++it > 5000000) {
        __hip_atomic_store(broken, 1, __ATOMIC_RELAXED, AGT);
        break;
      }
    }
  }
  __syncthreads();
}

#define RED16(a) { a += __shfl_xor(a, 1); a += __shfl_xor(a, 2); \
                   a += __shfl_xor(a, 4); a += __shfl_xor(a, 8); }

extern "C" __global__ void __launch_bounds__(NTH, 4)
memrnn_scan(const float* __restrict__ x, const float* __restrict__ U_w,
            const float* __restrict__ U_b, const float* __restrict__ V_w,
            const float* __restrict__ Ua_w, const float* __restrict__ Va_w,
            const float* __restrict__ vvec, float* __restrict__ out,
            char* __restrict__ wsb)
{
  const int blk  = blockIdx.x;
  const int b    = blk & 63;      // 4 blocks {b, b+64, b+128, b+192} per group
  const int q    = blk >> 6;
  const int tid  = threadIdx.x;
  const int lane = tid & 63;
  const int wav  = tid >> 6;
  const int r    = tid >> 4;      // gemv row 0..63 (16 threads/row)
  const int c    = tid & 15;
  const int gr   = q * SL + r;
  const int r2   = tid >> 2;      // parts gemv row 0..255 (4 threads/row)
  const int c2   = tid & 3;

  __half* mir   = (__half*)wsb + (size_t)blk * TT * SL;   // private fp16 h history
  float*  stw   = (float*)(wsb + STW_OFF);
  float*  ep    = (float*)(wsb + EP_OFF);
  float*  parts = (float*)(wsb + PARTS_OFF);
  int* aflag = (int*)(wsb + AF_OFF) + b * NQ * 32;
  int* bflag = (int*)(wsb + BF_OFF) + b * NQ * 32;
  int* pflag = (int*)(wsb + PF_OFF) + b * NQ * 32;
  int* broken = (int*)(wsb + BR_OFF);

  // persistent register weights
  float wV[16], wVa[16], wU[16], wUa2[16];
#pragma unroll
  for (int j = 0; j < 16; ++j) {
    const int i = j * 16 + c;
    wV[j]  = V_w [gr * HH + i];
    wVa[j] = Va_w[gr * HH + i];
    wU[j]  = U_w [gr * HH + i];
    wUa2[j] = Ua_w[r2 * HH + q * SL + c2 * 16 + j];   // own 64-col slice, all 256 rows
  }
  const float bias = U_b[gr];

  __shared__ __half  s_uam[SL * TT];   // [h][t2] premultiplied uam history, 128 KB
  __shared__ float2  s_av[SL];         // .x = PM*(Va*st)[h], .y = v[h]
  __shared__ float   s_e[TT];          // exp(e) weights
  __shared__ float   s_vec[HH];        // full st staging
  __shared__ float   s_x[HH];          // x row staging
  __shared__ float   s_hown[SL];       // own h slice staging
  __shared__ float   s_red[NW * SL];
  __shared__ float   s_d[NW];

  float* epg = ep + (size_t)(b * NQ + q) * TT;

  // ================= prologue (t = 0) =================
  if (tid < HH) s_x[tid] = x[(size_t)b * HH + tid];
  if (tid < SL) s_av[tid] = make_float2(0.f, vvec[q * SL + tid]);
  __syncthreads();
  {
    float acc = 0.f;
#pragma unroll
    for (int j = 0; j < 16; ++j) acc += wU[j] * s_x[j * 16 + c];
    RED16(acc);
    if (c == 0) st_cg(&stw[b * HH + gr], acc + bias);     // st0 (pre-tanh)
  }
  post1(bflag + q * 32);                                   // bflag -> 1
  float Vs = s_av[lane].y;                                 // slice v-sum
  Vs += __shfl_xor(Vs, 1);  Vs += __shfl_xor(Vs, 2);  Vs += __shfl_xor(Vs, 4);
  Vs += __shfl_xor(Vs, 8);  Vs += __shfl_xor(Vs, 16); Vs += __shfl_xor(Vs, 32);
  wait4(bflag, 1, broken);
  if (tid < HH) s_vec[tid] = ld_cg(&stw[b * HH + tid]);
  __syncthreads();
  if (tid < SL) {
    const float h0 = tanh_fast(s_vec[q * SL + tid]);       // V(hidden)=0 at t=0
    out[(size_t)b * HH + q * SL + tid] = h0;               // plain store
    mir[tid] = __float2half(h0);
    s_hown[tid] = h0;
  }
  {
    float acca = 0.f;
#pragma unroll
    for (int j = 0; j < 16; ++j) acca += wVa[j] * s_vec[j * 16 + c];
    RED16(acca);
    if (c == 0) s_av[r].x = PM * acca;
  }
  __syncthreads();
  {
    float pa = 0.f;
#pragma unroll
    for (int k = 0; k < 16; ++k) pa += wUa2[k] * s_hown[c2 * 16 + k];
    pa += __shfl_xor(pa, 1); pa += __shfl_xor(pa, 2);
    if (c2 == 0) st_cg(&parts[(size_t)(b * NQ + q) * HH + r2], pa);
  }
  post1(pflag + q * 32);                                   // pflag -> 1

  // ================= main loop =================
  for (int t = 1; t < TT; ++t) {
    // ---- P1: e-partials for t2 < t-1 from LDS history (conflict-free [h][t2]) ----
    for (int ci = wav; ci * SL < t - 1; ci += NW) {
      const int t2 = ci * SL + lane;
      const __half* up = s_uam + ci * SL + lane;
      float p2 = 0.f;
#pragma unroll 16
      for (int h = 0; h < SL; ++h) {
        const float2 av = s_av[h];                   // uniform broadcast
        const float uu = __half2float(up[h * TT]);
        const float rr = __builtin_amdgcn_rcpf(1.f + EXP2F(av.x + uu));
        p2 = fmaf(av.y, rr, p2);
      }
      if (t2 < t - 1) st_cg(&epg[t2], Vs - 2.f * p2);
    }
    // hidden poll: parts for t2 = t-1 (producers posted pflag=t at end of step t-1)
    wait4(pflag, t, broken);
    if (tid < SL) {
      const float* pp = parts + (size_t)b * NQ * HH + q * SL + tid;
      const float u4 = ld_cg(pp) + ld_cg(pp + HH) + ld_cg(pp + 2 * HH) + ld_cg(pp + 3 * HH);
      const float up_ = PM * u4;
      s_uam[tid * TT + (t - 1)] = __float2half(up_);
      const float2 av = s_av[tid];
      float term = av.y * __builtin_amdgcn_rcpf(1.f + EXP2F(av.x + up_));
      term += __shfl_xor(term, 1);  term += __shfl_xor(term, 2);  term += __shfl_xor(term, 4);
      term += __shfl_xor(term, 8);  term += __shfl_xor(term, 16); term += __shfl_xor(term, 32);
      if (tid == 0) st_cg(&epg[t - 1], Vs - 2.f * term);
    }
    post1(aflag + q * 32);                                 // aflag -> t
    wait4(aflag, t, broken);

    // ---- P2: weights (exp hoisted), softmax-weighted sum over private mirror ----
    if (tid < t) {
      const float* e0 = ep + (size_t)b * NQ * TT + tid;
      s_e[tid] = __expf(ld_cg(e0) + ld_cg(e0 + TT) + ld_cg(e0 + 2 * TT) + ld_cg(e0 + 3 * TT));
    }
    __syncthreads();
    {
      float num = 0.f, den = 0.f;
      const __half* mq = mir + lane;
#pragma unroll 8
      for (int t2 = wav; t2 < t; t2 += NW) {
        const float w = s_e[t2];
        den += w;
        num = fmaf(w, __half2float(mq[(size_t)t2 * SL]), num);
      }
      s_red[wav * SL + lane] = num;
      if (lane == 0) s_d[wav] = den;
    }
    __syncthreads();
    if (wav == 0) {
      float nt = 0.f, dt = 0.f;
#pragma unroll
      for (int w2 = 0; w2 < NW; ++w2) { nt += s_red[w2 * SL + lane]; dt += s_d[w2]; }
      const float ct  = nt / dt;
      const float stn = __half2float(mir[(size_t)(t - 1) * SL + lane]) + ct;  // last_h + ct
      st_cg(&stw[b * HH + q * SL + lane], stn);
    }
    float xv = 0.f;
    post1(bflag + q * 32);                                 // bflag -> t+1
    if (tid < HH) xv = x[((size_t)t * BB + b) * HH + tid]; // overlap with wait
    wait4(bflag, t + 1, broken);

    // ---- P3: h own rows; a' for next step; uam partials for all 256 rows ----
    if (tid < HH) { s_vec[tid] = ld_cg(&stw[b * HH + tid]); s_x[tid] = xv; }
    __syncthreads();
    {
      float acc = 0.f, acca = 0.f;
#pragma unroll
      for (int j = 0; j < 16; ++j) {
        const int i = j * 16 + c;
        const float sv = s_vec[i];
        acc  += wV[j] * sv + wU[j] * s_x[i];
        acca += wVa[j] * sv;
      }
      RED16(acc); RED16(acca);
      if (c == 0) {
        const float hv = tanh_fast(acc + bias);
        out[((size_t)t * BB + b) * HH + gr] = hv;          // plain store
        mir[(size_t)t * SL + r] = __float2half(hv);
        s_hown[r] = hv;
        s_av[r].x = PM * acca;
      }
    }
    if (t < TT - 1) {
      __syncthreads();
      float pa = 0.f;
#pragma unroll
      for (int k = 0; k < 16; ++k) pa += wUa2[k] * s_hown[c2 * 16 + k];
      pa += __shfl_xor(pa, 1); pa += __shfl_xor(pa, 2);
      if (c2 == 0) st_cg(&parts[(size_t)(b * NQ + q) * HH + r2], pa);
      post1(pflag + q * 32);                               // pflag -> t+1
    }
  }

  if (tid == 0 && __hip_atomic_load(broken, __ATOMIC_RELAXED, AGT))
    st_cg(&out[0], 1.0e6f);   // deadlock signature
}

__global__ void ws_sentinel(float* out) { out[0] = 2.0e6f; }

extern "C" void kernel_launch(void* const* d_in, const int* in_sizes, int n_in,
                              void* d_out, int out_size, void* d_ws, size_t ws_size,
                              hipStream_t stream) {
  const float* x    = (const float*)d_in[0];
  const float* U_w  = (const float*)d_in[1];
  const float* U_b  = (const float*)d_in[2];
  const float* V_w  = (const float*)d_in[3];
  const float* Ua_w = (const float*)d_in[4];
  const float* Va_w = (const float*)d_in[5];
  const float* v    = (const float*)d_in[6];
  float* out = (float*)d_out;

  if (ws_size < WS_NEED) {            // diagnosable failure (absmax ~2e6)
    ws_sentinel<<<1, 1, 0, stream>>>(out);
    return;
  }
  // zero all flag counters + broken each launch (graph-capturable)
  hipMemsetAsync((char*)d_ws + AF_OFF, 0, (size_t)(BR_OFF - AF_OFF) + 128, stream);
  memrnn_scan<<<dim3(BB * NQ), dim3(NTH), 0, stream>>>(
      x, U_w, U_b, V_w, Ua_w, Va_w, v, out, (char*)d_ws);
}